// Round 11
// baseline (127.426 us; speedup 1.0000x reference)
//
#include <hip/hip_runtime.h>

#define N_SERIES 1024
#define N_TIME 600
#define INPUT_SIZE 168
#define OUTPUT_SIZE 24
#define N_S 4
#define SEAS 24
#define N_WINDOWS (N_TIME - INPUT_SIZE - OUTPUT_SIZE + 1) /* 409 */
#define SEAS_LEN (N_TIME + SEAS)                          /* 624 */

#define INS_ELEMS (N_WINDOWS * N_SERIES * (INPUT_SIZE + N_S)) /* 72,036,352 */
#define OUTS_ELEMS (N_WINDOWS * N_SERIES * OUTPUT_SIZE)       /* 10,051,584 */
#define LEV_ELEMS (N_SERIES * N_TIME)
#define SEAS_ELEMS (N_SERIES * SEAS_LEN)

#define NQ_OUTS (OUTS_ELEMS / 4) /* 2,512,896 */

#define SCAN_BLOCKS 16
#define SCAN_T 64
#define COPY_BLOCKS 2032
#define WS_NEEDED (2u * LEV_ELEMS * sizeof(float)) /* tbl + llv = 4.9 MB */

/* ins2: one block owns SGRP series x all windows -> L1-resident reads */
#define INS2_BLOCKS 512
#define SGRP 2
#define TASKS_PER_W (SGRP * 43)               /* 86 */
#define TASKS_PER_G (N_WINDOWS * TASKS_PER_W) /* 35,174 */

typedef float f4 __attribute__((ext_vector_type(4)));

// Single-wave LDS phase fence: LDS ops within one wave retire in order, so no
// s_barrier / vmcnt drain — only a compiler scheduling fence between phases.
#define WAVE_FENCE()                                   \
    do {                                               \
        __builtin_amdgcn_wave_barrier();               \
        asm volatile("" ::: "memory");                 \
    } while (0)

// ---------------------------------------------------------------------------
// Kernel 1 (fused, UNCHANGED from R9/R10): blocks [0,16): exponential-
// smoothing scan (1 wave/block, register ring buffer, LDS-staged coalesced
// stores, no barriers). blocks [16,...): outsample window copy, nontemporal.
// ---------------------------------------------------------------------------
__global__ __launch_bounds__(SCAN_T) void scan_copy_kernel(
    const float* __restrict__ y, const float* __restrict__ embeds,
    const int* __restrict__ idxs, float* __restrict__ levels,
    float* __restrict__ seas1, f4* __restrict__ out_outs)
{
    __shared__ float b_lev[SCAN_T][25];
    __shared__ float b_sea[SCAN_T][25];

    if (blockIdx.x < SCAN_BLOCKS) {
        const int lane = threadIdx.x;
        const int s0 = blockIdx.x * SCAN_T;
        const int s = s0 + lane;
        const int row = idxs[s];
        const float* e = embeds + row * (2 + SEAS);

        const float lev_sms = 1.0f / (1.0f + __expf(-e[0]));
        const float seas_sms = 1.0f / (1.0f + __expf(-e[1]));
        const float one_m_lev = 1.0f - lev_sms;
        const float one_m_seas = 1.0f - seas_sms;

        const float* yrow = y + s * N_TIME;
        const f4* yv4 = (const f4*)yrow; // row stride 2400B keeps 16B align

        f4 cur[6], nxt[6];
#pragma unroll
        for (int i = 0; i < 6; ++i) cur[i] = yv4[i];

        float sb[SEAS];
#pragma unroll
        for (int j = 0; j < SEAS; ++j) {
            float v = __expf(e[2 + j]);
            sb[j] = v;
            b_sea[lane][j] = v;
        }
        WAVE_FENCE();
        // init seasonality cols 0..23: cooperative f4 stores (aligned)
#pragma unroll
        for (int k4 = 0; k4 < 6; ++k4) {
            int q4 = lane + k4 * SCAN_T;
            int r = q4 / 6;
            int c4 = q4 - r * 6;
            int cc = c4 * 4;
            f4 v = {b_sea[r][cc], b_sea[r][cc + 1], b_sea[r][cc + 2],
                    b_sea[r][cc + 3]};
            *(f4*)(seas1 + (s0 + r) * SEAS_LEN + cc) = v;
        }
        seas1[s * SEAS_LEN + SEAS] = sb[0]; // col 24 = rolled init_seas[0]
        float lev = __fdividef(cur[0].x, sb[0]);
        levels[s * N_TIME] = lev;
        WAVE_FENCE(); // b_sea reused below

        // ---- chunk 0: t = 1..23 (ring index = t), scalar store path ----
        {
#pragma unroll
            for (int i = 0; i < 6; ++i) nxt[i] = yv4[6 + i];
#pragma unroll
            for (int j = 0; j < 23; ++j) {
                const int t = j + 1;
                float yt = cur[t >> 2][t & 3];
                float st = sb[t];
                float q1 = __fdividef(yt, st);
                float newlev = lev_sms * q1 + one_m_lev * lev;
                float news =
                    seas_sms * __fdividef(yt, newlev) + one_m_seas * st;
                lev = newlev;
                sb[t] = news;
                b_lev[lane][j] = newlev;
                b_sea[lane][j] = news;
            }
            WAVE_FENCE();
#pragma unroll
            for (int k = 0; k < 24; ++k) {
                int i = lane + k * SCAN_T;
                int r = i / 24;
                int col = i - r * 24;
                if (col < 23) {
                    int sr = s0 + r;
                    levels[sr * N_TIME + 1 + col] = b_lev[r][col];
                    seas1[sr * SEAS_LEN + 25 + col] = b_sea[r][col];
                }
            }
            WAVE_FENCE();
#pragma unroll
            for (int i = 0; i < 6; ++i) cur[i] = nxt[i];
        }

        // ---- chunks c = 1..24: t = 24c + j, ring index = j ----
#pragma unroll 1
        for (int c = 1; c < 25; ++c) {
            const int t0 = 24 * c;
            if (c < 24) {
                const f4* p = (const f4*)(yrow + 24 * (c + 1));
#pragma unroll
                for (int i = 0; i < 6; ++i) nxt[i] = p[i];
            }
#pragma unroll
            for (int j = 0; j < 24; ++j) {
                float yt = cur[j >> 2][j & 3];
                float st = sb[j];
                float q1 = __fdividef(yt, st);
                float newlev = lev_sms * q1 + one_m_lev * lev;
                float news =
                    seas_sms * __fdividef(yt, newlev) + one_m_seas * st;
                lev = newlev;
                sb[j] = news;
                b_lev[lane][j] = newlev;
                b_sea[lane][j] = news;
            }
            WAVE_FENCE();
            // cooperative f4 stores: t0 = 24c -> 96c bytes, 16B-aligned
#pragma unroll
            for (int k4 = 0; k4 < 6; ++k4) {
                int q4 = lane + k4 * SCAN_T;
                int r = q4 / 6;
                int c4 = q4 - r * 6;
                int sr = s0 + r;
                int cc = c4 * 4;
                f4 vl = {b_lev[r][cc], b_lev[r][cc + 1], b_lev[r][cc + 2],
                         b_lev[r][cc + 3]};
                *(f4*)(levels + sr * N_TIME + t0 + cc) = vl;
                f4 vs = {b_sea[r][cc], b_sea[r][cc + 1], b_sea[r][cc + 2],
                         b_sea[r][cc + 3]};
                *(f4*)(seas1 + sr * SEAS_LEN + SEAS + t0 + cc) = vs;
            }
            WAVE_FENCE();
#pragma unroll
            for (int i = 0; i < 6; ++i) cur[i] = nxt[i];
        }
    } else {
        // copy role: outsample windows — dense wave-aligned, nontemporal
        int idx = (blockIdx.x - SCAN_BLOCKS) * SCAN_T + threadIdx.x;
        const int stride = (gridDim.x - SCAN_BLOCKS) * SCAN_T;
        for (; idx < NQ_OUTS; idx += stride) {
            int rowq = idx / 6;
            int j4 = idx - rowq * 6;
            int w = rowq >> 10;
            int s = rowq & 1023;
            const float* yp = y + s * N_TIME + w + INPUT_SIZE + j4 * 4;
            f4 v = {yp[0], yp[1], yp[2], yp[3]};
            __builtin_nontemporal_store(v, &out_outs[idx]);
        }
    }
}

// ---------------------------------------------------------------------------
// Kernel 2 (UNCHANGED): full-GPU parallel log pass:
//   tbl[s][t] = log(y/seas1), llv[s][t] = log(levels).
// ---------------------------------------------------------------------------
__global__ __launch_bounds__(256) void logpass_kernel(
    const float* __restrict__ y, const float* __restrict__ levels,
    const float* __restrict__ seas1, float* __restrict__ tbl,
    float* __restrict__ llv)
{
    int i = blockIdx.x * 256 + threadIdx.x; // f4 index over [0, 153600)
    int sr = i / 150;
    int c = i - sr * 150;
    f4 a = *((const f4*)(y + sr * N_TIME) + c);
    f4 se = *((const f4*)(seas1 + sr * SEAS_LEN) + c); // 2496B rows, aligned
    f4 l = *((const f4*)(levels + sr * N_TIME) + c);
    f4 ta, tl;
    ta.x = __logf(__fdividef(a.x, se.x));
    ta.y = __logf(__fdividef(a.y, se.y));
    ta.z = __logf(__fdividef(a.z, se.z));
    ta.w = __logf(__fdividef(a.w, se.w));
    tl.x = __logf(l.x);
    tl.y = __logf(l.y);
    tl.z = __logf(l.z);
    tl.w = __logf(l.w);
    ((f4*)tbl)[i] = ta;
    ((f4*)llv)[i] = tl;
}

// ---------------------------------------------------------------------------
// Kernel 3 (REDESIGNED — ownership locality): block b owns series
// [2b, 2b+2) x ALL 409 windows. Its entire read set (tbl/llv rows for 2
// series) is a ~1.4 KB sliding window -> L1-resident, reused ~114x in-block;
// global read traffic ~10 MB total, never contends with other XCDs, never
// evicted by the write stream. Task ql -> (w, sl, e4); output index
// w*44032 + s*43 + e4 is contiguous in ql within a w. NT dense stores.
// ---------------------------------------------------------------------------
__global__ __launch_bounds__(256) void ins2_kernel(
    const float* __restrict__ tbl, const float* __restrict__ llv,
    const float* __restrict__ y, const float* __restrict__ levels,
    const float* __restrict__ seas1, const float* __restrict__ s_matrix,
    f4* __restrict__ out_ins, int have_ws)
{
    const int s0 = blockIdx.x * SGRP;
    for (int ql = threadIdx.x; ql < TASKS_PER_G; ql += 256) {
        int w = ql / TASKS_PER_W;
        int slot = ql - w * TASKS_PER_W;
        int sl = slot / 43;
        int e4 = slot - sl * 43;
        int s = s0 + sl;
        f4 v;
        if (e4 == 42) {
            v = *(const f4*)(s_matrix + s * N_S);
        } else if (have_ws) {
            int t = w + e4 * 4;
            const float* tp = tbl + s * N_TIME + t;
            float lv = llv[s * N_TIME + w + INPUT_SIZE - 1];
            v.x = tp[0] - lv;
            v.y = tp[1] - lv;
            v.z = tp[2] - lv;
            v.w = tp[3] - lv;
        } else {
            int t = w + e4 * 4;
            float lev = levels[s * N_TIME + w + INPUT_SIZE - 1];
            const float* yp = y + s * N_TIME + t;
            const float* sp = seas1 + s * SEAS_LEN + t;
            v.x = __logf(__fdividef(yp[0], lev * sp[0]));
            v.y = __logf(__fdividef(yp[1], lev * sp[1]));
            v.z = __logf(__fdividef(yp[2], lev * sp[2]));
            v.w = __logf(__fdividef(yp[3], lev * sp[3]));
        }
        __builtin_nontemporal_store(v, &out_ins[w * 44032 + s * 43 + e4]);
    }
}

extern "C" void kernel_launch(void* const* d_in, const int* in_sizes, int n_in,
                              void* d_out, int out_size, void* d_ws, size_t ws_size,
                              hipStream_t stream) {
    const float* y      = (const float*)d_in[0];
    const float* sm     = (const float*)d_in[1];
    const float* embeds = (const float*)d_in[2];
    const int*   idxs   = (const int*)d_in[3];

    float* out      = (float*)d_out;
    float* out_ins  = out;
    float* out_outs = out + INS_ELEMS;
    float* out_lev  = out + INS_ELEMS + OUTS_ELEMS;
    float* out_seas = out_lev + LEV_ELEMS;

    float* tbl = (float*)d_ws;
    float* llv = tbl + LEV_ELEMS;
    const int have_ws = (ws_size >= (size_t)WS_NEEDED) ? 1 : 0;

    scan_copy_kernel<<<SCAN_BLOCKS + COPY_BLOCKS, SCAN_T, 0, stream>>>(
        y, embeds, idxs, out_lev, out_seas, (f4*)out_outs);
    if (have_ws) {
        logpass_kernel<<<LEV_ELEMS / 4 / 256, 256, 0, stream>>>(
            y, out_lev, out_seas, tbl, llv);
    }
    ins2_kernel<<<INS2_BLOCKS, 256, 0, stream>>>(
        tbl, llv, y, out_lev, out_seas, sm, (f4*)out_ins, have_ws);
}

// Round 12
// 112.509 us; speedup vs baseline: 1.1326x; 1.1326x over previous
//
#include <hip/hip_runtime.h>

#define N_SERIES 1024
#define N_TIME 600
#define INPUT_SIZE 168
#define OUTPUT_SIZE 24
#define N_S 4
#define SEAS 24
#define N_WINDOWS (N_TIME - INPUT_SIZE - OUTPUT_SIZE + 1) /* 409 */
#define SEAS_LEN (N_TIME + SEAS)                          /* 624 */

#define INS_ELEMS (N_WINDOWS * N_SERIES * (INPUT_SIZE + N_S)) /* 72,036,352 */
#define OUTS_ELEMS (N_WINDOWS * N_SERIES * OUTPUT_SIZE)       /* 10,051,584 */
#define LEV_ELEMS (N_SERIES * N_TIME)
#define SEAS_ELEMS (N_SERIES * SEAS_LEN)

#define NQ_OUTS (OUTS_ELEMS / 4) /* 2,512,896 */

#define SCAN_BLOCKS 16
#define SCAN_T 64
#define COPY_BLOCKS 2032

/* ins3: 256 blocks x 512 threads; block owns 4 series x all windows */
#define INS3_BLOCKS 256
#define INS3_T 512
#define TASKS_PER_W 172                       /* 4 series x 43 f4 */
#define TASKS_TOTAL (N_WINDOWS * TASKS_PER_W) /* 70,348 */

typedef float f4 __attribute__((ext_vector_type(4)));

// Single-wave LDS phase fence (scan kernel): LDS ops within one wave retire
// in order — only a compiler scheduling fence needed between phases.
#define WAVE_FENCE()                                   \
    do {                                               \
        __builtin_amdgcn_wave_barrier();               \
        asm volatile("" ::: "memory");                 \
    } while (0)

// ---------------------------------------------------------------------------
// Kernel 1 (fused, UNCHANGED): blocks [0,16): exponential-smoothing scan
// (1 wave/block, register ring buffer, LDS-staged coalesced f4 stores, no
// barriers). blocks [16,...): outsample window copy, nontemporal.
// ---------------------------------------------------------------------------
__global__ __launch_bounds__(SCAN_T) void scan_copy_kernel(
    const float* __restrict__ y, const float* __restrict__ embeds,
    const int* __restrict__ idxs, float* __restrict__ levels,
    float* __restrict__ seas1, f4* __restrict__ out_outs)
{
    __shared__ float b_lev[SCAN_T][25];
    __shared__ float b_sea[SCAN_T][25];

    if (blockIdx.x < SCAN_BLOCKS) {
        const int lane = threadIdx.x;
        const int s0 = blockIdx.x * SCAN_T;
        const int s = s0 + lane;
        const int row = idxs[s];
        const float* e = embeds + row * (2 + SEAS);

        const float lev_sms = 1.0f / (1.0f + __expf(-e[0]));
        const float seas_sms = 1.0f / (1.0f + __expf(-e[1]));
        const float one_m_lev = 1.0f - lev_sms;
        const float one_m_seas = 1.0f - seas_sms;

        const float* yrow = y + s * N_TIME;
        const f4* yv4 = (const f4*)yrow; // row stride 2400B keeps 16B align

        f4 cur[6], nxt[6];
#pragma unroll
        for (int i = 0; i < 6; ++i) cur[i] = yv4[i];

        float sb[SEAS];
#pragma unroll
        for (int j = 0; j < SEAS; ++j) {
            float v = __expf(e[2 + j]);
            sb[j] = v;
            b_sea[lane][j] = v;
        }
        WAVE_FENCE();
        // init seasonality cols 0..23: cooperative f4 stores (aligned)
#pragma unroll
        for (int k4 = 0; k4 < 6; ++k4) {
            int q4 = lane + k4 * SCAN_T;
            int r = q4 / 6;
            int c4 = q4 - r * 6;
            int cc = c4 * 4;
            f4 v = {b_sea[r][cc], b_sea[r][cc + 1], b_sea[r][cc + 2],
                    b_sea[r][cc + 3]};
            *(f4*)(seas1 + (s0 + r) * SEAS_LEN + cc) = v;
        }
        seas1[s * SEAS_LEN + SEAS] = sb[0]; // col 24 = rolled init_seas[0]
        float lev = __fdividef(cur[0].x, sb[0]);
        levels[s * N_TIME] = lev;
        WAVE_FENCE(); // b_sea reused below

        // ---- chunk 0: t = 1..23 (ring index = t), scalar store path ----
        {
#pragma unroll
            for (int i = 0; i < 6; ++i) nxt[i] = yv4[6 + i];
#pragma unroll
            for (int j = 0; j < 23; ++j) {
                const int t = j + 1;
                float yt = cur[t >> 2][t & 3];
                float st = sb[t];
                float q1 = __fdividef(yt, st);
                float newlev = lev_sms * q1 + one_m_lev * lev;
                float news =
                    seas_sms * __fdividef(yt, newlev) + one_m_seas * st;
                lev = newlev;
                sb[t] = news;
                b_lev[lane][j] = newlev;
                b_sea[lane][j] = news;
            }
            WAVE_FENCE();
#pragma unroll
            for (int k = 0; k < 24; ++k) {
                int i = lane + k * SCAN_T;
                int r = i / 24;
                int col = i - r * 24;
                if (col < 23) {
                    int sr = s0 + r;
                    levels[sr * N_TIME + 1 + col] = b_lev[r][col];
                    seas1[sr * SEAS_LEN + 25 + col] = b_sea[r][col];
                }
            }
            WAVE_FENCE();
#pragma unroll
            for (int i = 0; i < 6; ++i) cur[i] = nxt[i];
        }

        // ---- chunks c = 1..24: t = 24c + j, ring index = j ----
#pragma unroll 1
        for (int c = 1; c < 25; ++c) {
            const int t0 = 24 * c;
            if (c < 24) {
                const f4* p = (const f4*)(yrow + 24 * (c + 1));
#pragma unroll
                for (int i = 0; i < 6; ++i) nxt[i] = p[i];
            }
#pragma unroll
            for (int j = 0; j < 24; ++j) {
                float yt = cur[j >> 2][j & 3];
                float st = sb[j];
                float q1 = __fdividef(yt, st);
                float newlev = lev_sms * q1 + one_m_lev * lev;
                float news =
                    seas_sms * __fdividef(yt, newlev) + one_m_seas * st;
                lev = newlev;
                sb[j] = news;
                b_lev[lane][j] = newlev;
                b_sea[lane][j] = news;
            }
            WAVE_FENCE();
            // cooperative f4 stores: t0 = 24c -> 96c bytes, 16B-aligned
#pragma unroll
            for (int k4 = 0; k4 < 6; ++k4) {
                int q4 = lane + k4 * SCAN_T;
                int r = q4 / 6;
                int c4 = q4 - r * 6;
                int sr = s0 + r;
                int cc = c4 * 4;
                f4 vl = {b_lev[r][cc], b_lev[r][cc + 1], b_lev[r][cc + 2],
                         b_lev[r][cc + 3]};
                *(f4*)(levels + sr * N_TIME + t0 + cc) = vl;
                f4 vs = {b_sea[r][cc], b_sea[r][cc + 1], b_sea[r][cc + 2],
                         b_sea[r][cc + 3]};
                *(f4*)(seas1 + sr * SEAS_LEN + SEAS + t0 + cc) = vs;
            }
            WAVE_FENCE();
#pragma unroll
            for (int i = 0; i < 6; ++i) cur[i] = nxt[i];
        }
    } else {
        // copy role: outsample windows — dense wave-aligned, nontemporal
        int idx = (blockIdx.x - SCAN_BLOCKS) * SCAN_T + threadIdx.x;
        const int stride = (gridDim.x - SCAN_BLOCKS) * SCAN_T;
        for (; idx < NQ_OUTS; idx += stride) {
            int rowq = idx / 6;
            int j4 = idx - rowq * 6;
            int w = rowq >> 10;
            int s = rowq & 1023;
            const float* yp = y + s * N_TIME + w + INPUT_SIZE + j4 * 4;
            f4 v = {yp[0], yp[1], yp[2], yp[3]};
            __builtin_nontemporal_store(v, &out_outs[idx]);
        }
    }
}

// ---------------------------------------------------------------------------
// Kernel 3 (REDESIGNED — LDS-fed, 1 VMEM instr per output): block owns
// 4 series x all 409 windows. Staging computes the per-series log tables
// in-block (zero redundancy: 256 blocks x 4 series = 1024) into LDS:
//   tq[sl][t%4][t/4] = log(y[t]/seas1[t])  — mod-4 split turns the
//     stride-16B read pattern (t = w + 4*e4 + j) into stride-1 across lanes
//     -> conflict-free ds_read_b32;
//   lv[sl][t] = log(levels[t])             — broadcast reads (uniform per
//     segment).
// Main loop: 4-5 ds_read + 4 subs + ONE nontemporal store. Per (block,w)
// write run = 172 f4 = 2752 B = exactly 43 aligned cache lines (no partial
// lines). No workspace, no logpass kernel.
// ---------------------------------------------------------------------------
__global__ __launch_bounds__(INS3_T) void ins3_kernel(
    const float* __restrict__ y, const float* __restrict__ levels,
    const float* __restrict__ seas1, const float* __restrict__ s_matrix,
    f4* __restrict__ out_ins)
{
    __shared__ float tq[4][4][152]; // [series][t%4][t/4]
    __shared__ float lv[4][608];    // [series][t]
    __shared__ f4 sml[4];

    const int tid = threadIdx.x;
    const int s0 = blockIdx.x * 4;

    // ---- staging: 600 f4-tasks (4 series x 150 f4/row), logs computed here
    for (int i = tid; i < 600; i += INS3_T) {
        int sl = i / 150;
        int c = i - sl * 150; // f4 index within row; floats t = 4c..4c+3
        int s = s0 + sl;
        f4 yv = *((const f4*)(y + s * N_TIME) + c);
        f4 sv = *((const f4*)(seas1 + s * SEAS_LEN) + c);
        f4 lvv = *((const f4*)(levels + s * N_TIME) + c);
        // tq[sl][(4c+j)%4][(4c+j)/4] = tq[sl][j][c]
        tq[sl][0][c] = __logf(__fdividef(yv.x, sv.x));
        tq[sl][1][c] = __logf(__fdividef(yv.y, sv.y));
        tq[sl][2][c] = __logf(__fdividef(yv.z, sv.z));
        tq[sl][3][c] = __logf(__fdividef(yv.w, sv.w));
        f4 lg = {__logf(lvv.x), __logf(lvv.y), __logf(lvv.z), __logf(lvv.w)};
        *(f4*)(&lv[sl][4 * c]) = lg; // 16B-aligned (608%4==0)
    }
    if (tid < 4) sml[tid] = *((const f4*)s_matrix + (s0 + tid));
    __syncthreads();

    // ---- main loop: ql -> (w, sl, e4); out idx = w*44032 + s*43 + e4
    for (int ql = tid; ql < TASKS_TOTAL; ql += INS3_T) {
        unsigned uql = (unsigned)ql;
        int w = uql / 172u;
        int slot = ql - w * 172;
        int sl = (unsigned)slot / 43u;
        int e4 = slot - sl * 43;
        f4 v;
        if (e4 == 42) {
            v = sml[sl];
        } else {
            float l = lv[sl][w + INPUT_SIZE - 1];
            int a0 = w, a1 = w + 1, a2 = w + 2, a3 = w + 3;
            v.x = tq[sl][a0 & 3][(a0 >> 2) + e4] - l;
            v.y = tq[sl][a1 & 3][(a1 >> 2) + e4] - l;
            v.z = tq[sl][a2 & 3][(a2 >> 2) + e4] - l;
            v.w = tq[sl][a3 & 3][(a3 >> 2) + e4] - l;
        }
        __builtin_nontemporal_store(
            v, &out_ins[w * (N_SERIES * 43) + (s0 + sl) * 43 + e4]);
    }
}

extern "C" void kernel_launch(void* const* d_in, const int* in_sizes, int n_in,
                              void* d_out, int out_size, void* d_ws, size_t ws_size,
                              hipStream_t stream) {
    const float* y      = (const float*)d_in[0];
    const float* sm     = (const float*)d_in[1];
    const float* embeds = (const float*)d_in[2];
    const int*   idxs   = (const int*)d_in[3];

    float* out      = (float*)d_out;
    float* out_ins  = out;
    float* out_outs = out + INS_ELEMS;
    float* out_lev  = out + INS_ELEMS + OUTS_ELEMS;
    float* out_seas = out_lev + LEV_ELEMS;

    (void)d_ws; (void)ws_size;

    scan_copy_kernel<<<SCAN_BLOCKS + COPY_BLOCKS, SCAN_T, 0, stream>>>(
        y, embeds, idxs, out_lev, out_seas, (f4*)out_outs);
    ins3_kernel<<<INS3_BLOCKS, INS3_T, 0, stream>>>(
        y, out_lev, out_seas, sm, (f4*)out_ins);
}

// Round 13
// 103.454 us; speedup vs baseline: 1.2317x; 1.0875x over previous
//
#include <hip/hip_runtime.h>

#define N_SERIES 1024
#define N_TIME 600
#define INPUT_SIZE 168
#define OUTPUT_SIZE 24
#define N_S 4
#define SEAS 24
#define N_WINDOWS (N_TIME - INPUT_SIZE - OUTPUT_SIZE + 1) /* 409 */
#define SEAS_LEN (N_TIME + SEAS)                          /* 624 */

#define INS_ELEMS (N_WINDOWS * N_SERIES * (INPUT_SIZE + N_S)) /* 72,036,352 */
#define OUTS_ELEMS (N_WINDOWS * N_SERIES * OUTPUT_SIZE)       /* 10,051,584 */
#define LEV_ELEMS (N_SERIES * N_TIME)
#define SEAS_ELEMS (N_SERIES * SEAS_LEN)

#define NQ_OUTS (OUTS_ELEMS / 4)              /* 2,512,896 */
#define NQ_INS43 (N_WINDOWS * N_SERIES * 43)  /* 18,009,088 */
#define INS_SLICE (NQ_INS43 / 8)              /* 2,251,136 (43|SLICE, 64|SLICE) */

#define SCAN_BLOCKS 16
#define SCAN_T 64
#define COPY_BLOCKS 2032
#define INS_BLOCKS 2048
#define WS_NEEDED (2u * LEV_ELEMS * sizeof(float)) /* tbl + llv = 4.9 MB */

typedef float f4 __attribute__((ext_vector_type(4)));

// ---------------------------------------------------------------------------
// Kernel 1 (fused):
//   blocks [0,16): exponential-smoothing scan — ZERO LDS, ZERO fences.
//     Each lane owns one series end-to-end: 24-step chunks computed into
//     6+6 f4 register accumulators, stored directly to the lane's own row
//     (16B-aligned: byte offs 96c ≡ 0 mod 16). Stores are per-lane scattered
//     across rows — that's TA throughput only (~8 µs for 4.9 MB), vs the old
//     LDS-transpose path which exposed ~120cy ds_read latency 24x/chunk with
//     a single wave (no TLP to hide it). Cached stores (L2 merges the 16B
//     partial lines; NT would force HBM RMW — R11 lesson).
//   blocks [16,...): outsample window copy, dense wave-aligned, nontemporal.
// ---------------------------------------------------------------------------
__global__ __launch_bounds__(SCAN_T) void scan_copy_kernel(
    const float* __restrict__ y, const float* __restrict__ embeds,
    const int* __restrict__ idxs, float* __restrict__ levels,
    float* __restrict__ seas1, f4* __restrict__ out_outs)
{
    if (blockIdx.x < SCAN_BLOCKS) {
        const int lane = threadIdx.x;
        const int s = blockIdx.x * SCAN_T + lane;
        const int row = idxs[s];
        const float* e = embeds + row * (2 + SEAS);

        const float lev_sms = 1.0f / (1.0f + __expf(-e[0]));
        const float seas_sms = 1.0f / (1.0f + __expf(-e[1]));
        const float one_m_lev = 1.0f - lev_sms;
        const float one_m_seas = 1.0f - seas_sms;

        const float* yrow = y + s * N_TIME;
        const f4* yv4 = (const f4*)yrow; // row stride 2400B keeps 16B align
        float* lrow = levels + s * N_TIME;   // byte base s*2400, 16B-aligned
        float* srow = seas1 + s * SEAS_LEN;  // byte base s*2496, 16B-aligned

        f4 cur[6], nxt[6];
#pragma unroll
        for (int i = 0; i < 6; ++i) cur[i] = yv4[i];

        float sb[SEAS];
#pragma unroll
        for (int j = 0; j < SEAS; ++j) sb[j] = __expf(e[2 + j]);

        // init seasonality cols 0..23 straight from registers
#pragma unroll
        for (int k = 0; k < 6; ++k) {
            f4 v = {sb[4 * k], sb[4 * k + 1], sb[4 * k + 2], sb[4 * k + 3]};
            *(f4*)(srow + 4 * k) = v;
        }

        float lev = __fdividef(cur[0].x, sb[0]);

        f4 fl[6], fs[6];
        // ---- chunk 0: t = 1..23 (ring index = t); slot t=0 carries the
        //      specials: levels[0] = level0, seas col 24 = init sb[0].
        fl[0].x = lev;
        fs[0].x = sb[0];
        {
#pragma unroll
            for (int i = 0; i < 6; ++i) nxt[i] = yv4[6 + i];
#pragma unroll
            for (int j = 1; j < 24; ++j) {
                float yt = cur[j >> 2][j & 3];
                float st = sb[j];
                float q1 = __fdividef(yt, st);
                float newlev = lev_sms * q1 + one_m_lev * lev;
                float news =
                    seas_sms * __fdividef(yt, newlev) + one_m_seas * st;
                lev = newlev;
                sb[j] = news;
                fl[j >> 2][j & 3] = newlev;
                fs[j >> 2][j & 3] = news;
            }
#pragma unroll
            for (int k = 0; k < 6; ++k) {
                *(f4*)(lrow + 4 * k) = fl[k];            // levels t=0..23
                *(f4*)(srow + SEAS + 4 * k) = fs[k];     // seas cols 24..47
            }
#pragma unroll
            for (int i = 0; i < 6; ++i) cur[i] = nxt[i];
        }

        // ---- chunks c = 1..24: t = 24c + j, ring index = j ----
#pragma unroll 1
        for (int c = 1; c < 25; ++c) {
            const int t0 = 24 * c;
            if (c < 24) {
                const f4* p = (const f4*)(yrow + 24 * (c + 1));
#pragma unroll
                for (int i = 0; i < 6; ++i) nxt[i] = p[i];
            }
#pragma unroll
            for (int j = 0; j < 24; ++j) {
                float yt = cur[j >> 2][j & 3];
                float st = sb[j];
                float q1 = __fdividef(yt, st);
                float newlev = lev_sms * q1 + one_m_lev * lev;
                float news =
                    seas_sms * __fdividef(yt, newlev) + one_m_seas * st;
                lev = newlev;
                sb[j] = news;
                fl[j >> 2][j & 3] = newlev;
                fs[j >> 2][j & 3] = news;
            }
#pragma unroll
            for (int k = 0; k < 6; ++k) {
                *(f4*)(lrow + t0 + 4 * k) = fl[k];
                *(f4*)(srow + SEAS + t0 + 4 * k) = fs[k];
            }
#pragma unroll
            for (int i = 0; i < 6; ++i) cur[i] = nxt[i];
        }
    } else {
        // copy role: outsample windows — dense wave-aligned, nontemporal
        int idx = (blockIdx.x - SCAN_BLOCKS) * SCAN_T + threadIdx.x;
        const int stride = (gridDim.x - SCAN_BLOCKS) * SCAN_T;
        for (; idx < NQ_OUTS; idx += stride) {
            int rowq = idx / 6;
            int j4 = idx - rowq * 6;
            int w = rowq >> 10;
            int s = rowq & 1023;
            const float* yp = y + s * N_TIME + w + INPUT_SIZE + j4 * 4;
            f4 v = {yp[0], yp[1], yp[2], yp[3]};
            __builtin_nontemporal_store(v, &out_outs[idx]);
        }
    }
}

// ---------------------------------------------------------------------------
// Kernel 2 (R9 verbatim): full-GPU parallel log pass:
//   tbl[s][t] = log(y/seas1), llv[s][t] = log(levels).
// ---------------------------------------------------------------------------
__global__ __launch_bounds__(256) void logpass_kernel(
    const float* __restrict__ y, const float* __restrict__ levels,
    const float* __restrict__ seas1, float* __restrict__ tbl,
    float* __restrict__ llv)
{
    int i = blockIdx.x * 256 + threadIdx.x; // f4 index over [0, 153600)
    int sr = i / 150;
    int c = i - sr * 150;
    f4 a = *((const f4*)(y + sr * N_TIME) + c);
    f4 se = *((const f4*)(seas1 + sr * SEAS_LEN) + c); // 2496B rows, aligned
    f4 l = *((const f4*)(levels + sr * N_TIME) + c);
    f4 ta, tl;
    ta.x = __logf(__fdividef(a.x, se.x));
    ta.y = __logf(__fdividef(a.y, se.y));
    ta.z = __logf(__fdividef(a.z, se.z));
    ta.w = __logf(__fdividef(a.w, se.w));
    tl.x = __logf(l.x);
    tl.y = __logf(l.y);
    tl.z = __logf(l.z);
    tl.w = __logf(l.w);
    ((f4*)tbl)[i] = ta;
    ((f4*)llv)[i] = tl;
}

// ---------------------------------------------------------------------------
// Kernel 3 (R9 verbatim — best known): insample rows incl. static column.
// XCD-clustered 1/8 q-slices; NT stores (wave-aligned full lines);
// incremental rowq/e4 (65536 = 43*1524 + 4).
// ---------------------------------------------------------------------------
__global__ __launch_bounds__(256) void ins_kernel(
    const float* __restrict__ tbl, const float* __restrict__ llv,
    const float* __restrict__ s_matrix, f4* __restrict__ out_ins)
{
    const f4* sm4 = (const f4*)s_matrix;
    const int xcd = blockIdx.x & 7;
    const int lb = blockIdx.x >> 3; // 0..255
    const int qend = (xcd + 1) * INS_SLICE;
    const int stride = (INS_BLOCKS / 8) * 256; /* 65536 */
    int q = xcd * INS_SLICE + lb * 256 + (int)threadIdx.x;
    int rowq = q / 43;
    int e4 = q - rowq * 43;
    for (; q < qend; q += stride) {
        int w = rowq >> 10;
        int s = rowq & 1023;
        f4 v;
        if (e4 == 42) {
            v = sm4[s];
        } else {
            int t = w + e4 * 4;
            const float* tp = tbl + s * N_TIME + t;
            float lv = llv[s * N_TIME + w + INPUT_SIZE - 1];
            v.x = tp[0] - lv;
            v.y = tp[1] - lv;
            v.z = tp[2] - lv;
            v.w = tp[3] - lv;
        }
        __builtin_nontemporal_store(v, &out_ins[q]);
        rowq += 1524;
        e4 += 4;
        if (e4 >= 43) {
            e4 -= 43;
            rowq += 1;
        }
    }
}

// Fallback (ws too small): compute logs on the fly, same XCD clustering.
__global__ __launch_bounds__(256) void ins_kernel_fb(
    const float* __restrict__ y, const float* __restrict__ levels,
    const float* __restrict__ seas1, const float* __restrict__ s_matrix,
    f4* __restrict__ out_ins)
{
    const f4* sm4 = (const f4*)s_matrix;
    const int xcd = blockIdx.x & 7;
    const int lb = blockIdx.x >> 3;
    const int qend = (xcd + 1) * INS_SLICE;
    const int stride = (INS_BLOCKS / 8) * 256;
    for (int q = xcd * INS_SLICE + lb * 256 + (int)threadIdx.x; q < qend;
         q += stride) {
        int rowq = q / 43;
        int e4 = q - rowq * 43;
        int w = rowq >> 10;
        int s = rowq & 1023;
        f4 v;
        if (e4 == 42) {
            v = sm4[s];
        } else {
            int t = w + e4 * 4;
            float lev = levels[s * N_TIME + w + INPUT_SIZE - 1];
            const float* yp = y + s * N_TIME + t;
            const float* sp = seas1 + s * SEAS_LEN + t;
            float vv[4];
#pragma unroll
            for (int j = 0; j < 4; ++j)
                vv[j] = __logf(__fdividef(yp[j], lev * sp[j]));
            v.x = vv[0]; v.y = vv[1]; v.z = vv[2]; v.w = vv[3];
        }
        __builtin_nontemporal_store(v, &out_ins[q]);
    }
}

extern "C" void kernel_launch(void* const* d_in, const int* in_sizes, int n_in,
                              void* d_out, int out_size, void* d_ws, size_t ws_size,
                              hipStream_t stream) {
    const float* y      = (const float*)d_in[0];
    const float* sm     = (const float*)d_in[1];
    const float* embeds = (const float*)d_in[2];
    const int*   idxs   = (const int*)d_in[3];

    float* out      = (float*)d_out;
    float* out_ins  = out;
    float* out_outs = out + INS_ELEMS;
    float* out_lev  = out + INS_ELEMS + OUTS_ELEMS;
    float* out_seas = out_lev + LEV_ELEMS;

    float* tbl = (float*)d_ws;
    float* llv = tbl + LEV_ELEMS;
    const int have_ws = (ws_size >= (size_t)WS_NEEDED) ? 1 : 0;

    scan_copy_kernel<<<SCAN_BLOCKS + COPY_BLOCKS, SCAN_T, 0, stream>>>(
        y, embeds, idxs, out_lev, out_seas, (f4*)out_outs);
    if (have_ws) {
        logpass_kernel<<<LEV_ELEMS / 4 / 256, 256, 0, stream>>>(
            y, out_lev, out_seas, tbl, llv);
        ins_kernel<<<INS_BLOCKS, 256, 0, stream>>>(tbl, llv, sm,
                                                   (f4*)out_ins);
    } else {
        ins_kernel_fb<<<INS_BLOCKS, 256, 0, stream>>>(y, out_lev, out_seas,
                                                      sm, (f4*)out_ins);
    }
}